// Round 10
// baseline (41.737 us; speedup 1.0000x reference)
//
#include <hip/hip_runtime.h>
#include <hip/hip_bf16.h>
#include <math.h>

// R10 = COUNTER-VISIBILITY PROBE: exact R9 body, grid x5. Passes 2-5 recompute
// identical pillars and write identical bytes (deterministic -> safe). Purpose:
// single ~50us dispatch cracks the rocprof top-5 (harness fills are 40-44us),
// finally exposing OUR VALUBusy / FETCH_SIZE / VGPR_Count / MfmaUtil to
// discriminate exec-bound vs latency-bound vs cache-churn. R9 (16.24us)
// remains the best real kernel; this round is a measurement.

#define NPIL  40000
#define NITER 10
#define WPB   4
#define BLOCK (WPB * 64)
#define NBLK  (NPIL / (WPB * NITER))   // 1000 logical blocks
#define PASSES 5

typedef float f32x16 __attribute__((ext_vector_type(16)));
typedef short bf16x8 __attribute__((ext_vector_type(8)));

union frag_u { bf16x8 h; int4 w; };

__device__ __forceinline__ int pk(float a, float b) {
    unsigned lo = (unsigned)__bfloat16_as_ushort(__float2bfloat16(a));
    unsigned hi = (unsigned)__bfloat16_as_ushort(__float2bfloat16(b));
    return (int)(lo | (hi << 16));
}
__device__ __forceinline__ float bfround(float x) {
    return __bfloat162float(__float2bfloat16(x));
}

template<int CTRL>
__device__ __forceinline__ float dpp_add(float x) {
    return x + __int_as_float(__builtin_amdgcn_update_dpp(
        0, __float_as_int(x), CTRL, 0xF, 0xF, true));
}
__device__ __forceinline__ float lo32_sum(float x) {
    x = dpp_add<0x111>(x);   // row_shr:1
    x = dpp_add<0x112>(x);   // row_shr:2
    x = dpp_add<0x114>(x);   // row_shr:4
    x = dpp_add<0x118>(x);   // row_shr:8
    x = dpp_add<0x142>(x);   // row_bcast:15 -> lane31 = sum(0..31)
    return __int_as_float(__builtin_amdgcn_readlane(__float_as_int(x), 31));
}

__device__ __forceinline__ float vmax16(const f32x16& a) {
    float t0 = fmaxf(fmaxf(a[0],  a[1]),  a[2]);
    float t1 = fmaxf(fmaxf(a[3],  a[4]),  a[5]);
    float t2 = fmaxf(fmaxf(a[6],  a[7]),  a[8]);
    float t3 = fmaxf(fmaxf(a[9],  a[10]), a[11]);
    float t4 = fmaxf(fmaxf(a[12], a[13]), a[14]);
    float u0 = fmaxf(fmaxf(t0, t1), t2);
    float u1 = fmaxf(fmaxf(t3, t4), a[15]);
    return fmaxf(u0, u1);
}

__global__ __launch_bounds__(BLOCK, 4)
void pfn_mfma_kernel(const float* __restrict__ features,   // [N,32,4]
                     const int*   __restrict__ num_voxels, // [N]
                     const int*   __restrict__ coors,      // [N,4]
                     const float* __restrict__ Wm,         // [64,9]
                     const float* __restrict__ gamma,
                     const float* __restrict__ beta,
                     const float* __restrict__ rmean,
                     const float* __restrict__ rvar,
                     float* __restrict__ out)               // [N,64]
{
    __shared__ int4 sfrag0[64];
    __shared__ int4 sfrag1[64];

    const int  lane = threadIdx.x & 63;
    const int  wid  = threadIdx.x >> 6;
    const int  lo31 = lane & 31;
    const bool hih  = (lane >= 32);

    const int lblk = blockIdx.x % NBLK;                // passes 2-5 duplicate pass 1
    const int p0   = (lblk * WPB + wid) * NITER;       // 10 contiguous pillars

    const float* fbase = features + (size_t)p0 * 128 + lo31 * 4;
    float4 qv[NITER];
    #pragma unroll
    for (int j = 0; j < NITER; ++j)
        qv[j] = *reinterpret_cast<const float4*>(fbase + (size_t)j * 128);
    const int  li  = (lane < NITER) ? lane : (NITER - 1);
    const int  nv8 = num_voxels[p0 + li];
    const int2 cc8 = *reinterpret_cast<const int2*>(coors + (p0 + li) * 4 + 2);

    if (wid == 0) {
        #pragma unroll
        for (int t = 0; t < 2; ++t) {
            const int uu = lo31 + t * 32;
            const float* w = Wm + uu * 9;
            const float s  = gamma[uu] * rsqrtf(rvar[uu] + 1e-3f);
            const float tb = beta[uu] - rmean[uu] * s;
            int4 r;
            if (!hih) {
                r.x = pk((w[0] + w[4] + w[7]) * s, (w[1] + w[5] + w[8]) * s);
                r.y = pk((w[2] + w[6]) * s,        w[3] * s);
                r.z = pk(w[4] * s,                 w[5] * s);
                r.w = pk(w[6] * s,                 0.0f);
            } else {
                const float w7s = w[7] * s, w8s = w[8] * s;
                r.x = pk(w7s, w7s);
                r.y = pk(w8s, w8s);
                r.z = pk(tb,  tb - bfround(tb));   // (tb_hi, tb_lo)
                r.w = 0;
            }
            if (t == 0) sfrag0[lane] = r; else sfrag1[lane] = r;
        }
    }
    __syncthreads();

    frag_u bf0, bf1;
    bf0.w = sfrag0[lane];
    bf1.w = sfrag1[lane];

    f32x16 z;
    #pragma unroll
    for (int i = 0; i < 16; ++i) z[i] = 0.0f;

    const int ONE2 = 0x3F803F80;
    const int inv2 = hih ? ONE2 : 0;

    #pragma unroll
    for (int j = 0; j < NITER; ++j) {
        const int   snv = __builtin_amdgcn_readlane(nv8,   j);
        const int   sc2 = __builtin_amdgcn_readlane(cc8.x, j);
        const int   sc3 = __builtin_amdgcn_readlane(cc8.y, j);
        const float4 q  = qv[j];

        const float S0 = lo32_sum(q.x);
        const float S1 = lo32_sum(q.y);
        const float S2 = lo32_sum(q.z);
        const float rn = __builtin_amdgcn_rcpf((float)snv);
        const float cx = (float)sc3 * 0.2f + 0.1f;
        const float cy = (float)sc2 * 0.2f + (0.1f - 40.0f);

        const int f01 = pk(q.x, q.y);
        const int f23 = pk(q.z, q.w);
        const int mxy = pk(-S0 * rn, -S1 * rn);
        const int mz0 = pk(-S2 * rn, 0.0f);
        const int cxw = pk(-cx, -cx - bfround(-cx));
        const int cyw = pk(-cy, -cy - bfround(-cy));

        const bool valid = (lo31 < snv);
        int w0 = hih ? cxw  : f01;  w0 = valid ? w0 : 0;
        int w1 = hih ? cyw  : f23;  w1 = valid ? w1 : 0;
        int w2 = hih ? ONE2 : mxy;  w2 = valid ? w2 : inv2;
        int w3 = hih ? 0    : mz0;  w3 = valid ? w3 : 0;
        frag_u af; af.w = make_int4(w0, w1, w2, w3);

        const f32x16 a0 = __builtin_amdgcn_mfma_f32_32x32x16_bf16(af.h, bf0.h, z, 0, 0, 0);
        const f32x16 a1 = __builtin_amdgcn_mfma_f32_32x32x16_bf16(af.h, bf1.h, z, 0, 0, 0);

        const float m0 = vmax16(a0);
        const float m1 = vmax16(a1);
        const float got  = __shfl_xor(hih ? m0 : m1, 32, 64);
        const float mine = hih ? m1 : m0;
        const float r = fmaxf(fmaxf(mine, got), 0.0f);

        out[(size_t)(p0 + j) * 64 + lane] = r;
    }
}

extern "C" void kernel_launch(void* const* d_in, const int* in_sizes, int n_in,
                              void* d_out, int out_size, void* d_ws, size_t ws_size,
                              hipStream_t stream) {
    const float* features   = (const float*)d_in[0];
    const int*   num_voxels = (const int*)  d_in[1];
    const int*   coors      = (const int*)  d_in[2];
    const float* Wm         = (const float*)d_in[3];
    const float* gamma      = (const float*)d_in[4];
    const float* beta       = (const float*)d_in[5];
    const float* rmean      = (const float*)d_in[6];
    const float* rvar       = (const float*)d_in[7];
    float*       out        = (float*)d_out;

    hipLaunchKernelGGL(pfn_mfma_kernel, dim3(NBLK * PASSES), dim3(BLOCK), 0, stream,
                       features, num_voxels, coors, Wm, gamma, beta, rmean, rvar, out);
}

// Round 11
// 13.889 us; speedup vs baseline: 3.0051x; 3.0051x over previous
//
#include <hip/hip_runtime.h>
#include <hip/hip_bf16.h>
#include <math.h>

// R11: VALU diet + occupancy, driven by R10's counters (VALUBusy 63%, VGPR 44,
// Occupancy 40% -> exec-bound, grid-limited, prefetch was phantom).
// MFMA computes ONLY the per-point dot:  d_p = bf16dot(feat_p, Acoef) ,
// with padding masked inside via k4: A.k4 = (row invalid ? 1.0 : 0), B.k4 = -1e30.
// Everything row-constant (mean/center/BN bias) is B, f32, added AFTER the max:
//   max_p(d_p + B) = max_p(d_p) + B.
// Wave 0 of each block builds per-lane B-frags AND f32 fold-consts into LDS.

#define NPIL  40000
#define PPTS  32
#define NITER 5
#define WPB   4
#define BLOCK (WPB * 64)
#define NBLK  (NPIL / (WPB * NITER))   // 2000 blocks = 8000 waves (~6/SIMD)

typedef float f32x16 __attribute__((ext_vector_type(16)));
typedef short bf16x8 __attribute__((ext_vector_type(8)));

union frag_u { bf16x8 h; int4 w; };

__device__ __forceinline__ int pk(float a, float b) {   // v_cvt_pk_bf16_f32
    unsigned lo = (unsigned)__bfloat16_as_ushort(__float2bfloat16(a));
    unsigned hi = (unsigned)__bfloat16_as_ushort(__float2bfloat16(b));
    return (int)(lo | (hi << 16));
}

template<int CTRL>
__device__ __forceinline__ float dpp_add(float x) {
    return x + __int_as_float(__builtin_amdgcn_update_dpp(
        0, __float_as_int(x), CTRL, 0xF, 0xF, true));
}
// sum over lanes 0..31, broadcast to all lanes
__device__ __forceinline__ float lo32_sum(float x) {
    x = dpp_add<0x111>(x);   // row_shr:1
    x = dpp_add<0x112>(x);   // row_shr:2
    x = dpp_add<0x114>(x);   // row_shr:4
    x = dpp_add<0x118>(x);   // row_shr:8
    x = dpp_add<0x142>(x);   // row_bcast:15 -> lane31 = sum(0..31)
    return __int_as_float(__builtin_amdgcn_readlane(__float_as_int(x), 31));
}

__device__ __forceinline__ float vmax16(const f32x16& a) {   // max3-fusable tree
    float t0 = fmaxf(fmaxf(a[0],  a[1]),  a[2]);
    float t1 = fmaxf(fmaxf(a[3],  a[4]),  a[5]);
    float t2 = fmaxf(fmaxf(a[6],  a[7]),  a[8]);
    float t3 = fmaxf(fmaxf(a[9],  a[10]), a[11]);
    float t4 = fmaxf(fmaxf(a[12], a[13]), a[14]);
    float u0 = fmaxf(fmaxf(t0, t1), t2);
    float u1 = fmaxf(fmaxf(t3, t4), a[15]);
    return fmaxf(u0, u1);
}

__global__ __launch_bounds__(BLOCK, 6)
void pfn_mfma_kernel(const float* __restrict__ features,   // [N,32,4]
                     const int*   __restrict__ num_voxels, // [N]
                     const int*   __restrict__ coors,      // [N,4]
                     const float* __restrict__ Wm,         // [64,9]
                     const float* __restrict__ gamma,
                     const float* __restrict__ beta,
                     const float* __restrict__ rmean,
                     const float* __restrict__ rvar,
                     float* __restrict__ out)               // [N,64]
{
    __shared__ int4   sB0[64];   // B-frag, units 0-31  (16B stride: conflict-free)
    __shared__ int4   sB1[64];   // B-frag, units 32-63
    __shared__ float4 sC0[64];   // (W4s, W5s, W6s, tb) per unit=index
    __shared__ float2 sC1[64];   // (W7s, W8s)

    const int  lane = threadIdx.x & 63;
    const int  wid  = threadIdx.x >> 6;
    const int  lo31 = lane & 31;
    const bool hih  = (lane >= 32);

    const int p0 = (blockIdx.x * WPB + wid) * NITER;   // 5 contiguous pillars

    // ---- per-wave loads (issue before barrier; latency hides under build) ----
    const float* fbase = features + (size_t)p0 * 128 + lo31 * 4;
    float4 qv[NITER];
    #pragma unroll
    for (int j = 0; j < NITER; ++j)
        qv[j] = *reinterpret_cast<const float4*>(fbase + (size_t)j * 128);
    const int  li  = (lane < NITER) ? lane : (NITER - 1);
    const int  nv8 = num_voxels[p0 + li];                                   // lane j -> pillar j
    const int2 cc8 = *reinterpret_cast<const int2*>(coors + (p0 + li) * 4 + 2);

    // ---- wave 0 builds frags + f32 consts ONCE per block (unit = lane) ----
    if (wid == 0) {
        const float* w  = Wm + lane * 9;
        const float  s  = gamma[lane] * rsqrtf(rvar[lane] + 1e-3f);
        const float  tb = beta[lane] - rmean[lane] * s;
        int4 mypk;
        mypk.x = pk((w[0] + w[4] + w[7]) * s, (w[1] + w[5] + w[8]) * s);
        mypk.y = pk((w[2] + w[6]) * s,        w[3] * s);
        mypk.z = pk(-1e30f, 0.0f);            // k4 = -1e30 kill-column
        mypk.w = 0;
        const int4 zero4 = make_int4(0, 0, 0, 0);
        if (!hih) { sB0[lane] = mypk;  sB1[lane + 32] = zero4; }   // hi half of frags = 0
        else      { sB1[lane - 32] = mypk;  sB0[lane] = zero4; }
        sC0[lane] = make_float4(w[4] * s, w[5] * s, w[6] * s, tb);
        sC1[lane] = make_float2(w[7] * s, w[8] * s);
    }
    __syncthreads();

    frag_u bf0, bf1;
    bf0.w = sB0[lane];
    bf1.w = sB1[lane];
    const float4 c0 = sC0[lane];    // W4s, W5s, W6s, tb
    const float2 c1 = sC1[lane];    // W7s, W8s
    const float  tb = c0.w;

    f32x16 z;
    #pragma unroll
    for (int i = 0; i < 16; ++i) z[i] = 0.0f;

    const int flagw = hih ? 0 : 0x3F80;   // bf16 1.0 in k4 (low short of word2), lo lanes only

    #pragma unroll
    for (int j = 0; j < NITER; ++j) {
        const int   snv = __builtin_amdgcn_readlane(nv8,   j);
        const int   sc2 = __builtin_amdgcn_readlane(cc8.x, j);
        const int   sc3 = __builtin_amdgcn_readlane(cc8.y, j);
        const float4 q  = qv[j];

        // ---- B (row-constant, f32): mean over ALL 32 pts / nv, centers, bias ----
        const float S0 = lo32_sum(q.x);
        const float S1 = lo32_sum(q.y);
        const float S2 = lo32_sum(q.z);
        const float rn = __builtin_amdgcn_rcpf((float)snv);   // |err|~1e-7, harmless
        const float cx = (float)sc3 * 0.2f + 0.1f;
        const float cy = (float)sc2 * 0.2f + (0.1f - 40.0f);
        float B = tb;
        B = fmaf(-(S0 * rn), c0.x, B);
        B = fmaf(-(S1 * rn), c0.y, B);
        B = fmaf(-(S2 * rn), c0.z, B);
        B = fmaf(-cx, c1.x, B);
        B = fmaf(-cy, c1.y, B);

        // ---- A-frag: k0-3 = bf16 features, k4 = invalid flag; rows >= nv zeroed.
        // valid uses LANE (not lo31): hi lanes (k8-15 slots) auto-zero.
        const int f01 = pk(q.x, q.y);
        const int f23 = pk(q.z, q.w);
        const bool valid = (lane < snv);
        frag_u af;
        af.w = make_int4(valid ? f01 : 0,
                         valid ? f23 : 0,
                         valid ? 0 : flagw,
                         0);

        const f32x16 a0 = __builtin_amdgcn_mfma_f32_32x32x16_bf16(af.h, bf0.h, z, 0, 0, 0);
        const f32x16 a1 = __builtin_amdgcn_mfma_f32_32x32x16_bf16(af.h, bf1.h, z, 0, 0, 0);

        // ---- max over 32 rows (invalid rows = -1e30), one lane^32 exchange ----
        const float m0 = vmax16(a0);
        const float m1 = vmax16(a1);
        const float got  = __shfl_xor(hih ? m0 : m1, 32, 64);
        const float mine = hih ? m1 : m0;
        float r = fmaxf(fmaxf(mine, got) + B, 0.0f);          // relu folded
        r = fmaxf(r, (snv < PPTS) ? tb : -INFINITY);          // padded rows -> relu(tb)

        out[(size_t)(p0 + j) * 64 + lane] = r;
    }
}

extern "C" void kernel_launch(void* const* d_in, const int* in_sizes, int n_in,
                              void* d_out, int out_size, void* d_ws, size_t ws_size,
                              hipStream_t stream) {
    const float* features   = (const float*)d_in[0];
    const int*   num_voxels = (const int*)  d_in[1];
    const int*   coors      = (const int*)  d_in[2];
    const float* Wm         = (const float*)d_in[3];
    const float* gamma      = (const float*)d_in[4];
    const float* beta       = (const float*)d_in[5];
    const float* rmean      = (const float*)d_in[6];
    const float* rvar       = (const float*)d_in[7];
    float*       out        = (float*)d_out;

    hipLaunchKernelGGL(pfn_mfma_kernel, dim3(NBLK), dim3(BLOCK), 0, stream,
                       features, num_voxels, coors, Wm, gamma, beta, rmean, rvar, out);
}